// Round 8
// baseline (124.244 us; speedup 1.0000x reference)
//
#include <hip/hip_runtime.h>
#include <hip/hip_fp16.h>
#include <math.h>

// Problem constants
#define T_LEN 131072
#define NCH   32
#define NBAT  4
#define WIN   512
#define HOP   256
#define NFR   512            // frames per (b,c) = T/HOP
#define NBIN  257            // rfft bins
#define NBC   (NBAT*NCH)     // 128
#define FPB   4              // frames per chunk (one wave per chunk)
#define NBLK  (NFR/FPB)      // 128 chunks per bc
#define TWOPI 6.28318530717958647692f

// XOR swizzle for FFT LDS float2 arrays (hits the b64 4-lane/bank floor)
#define SWZ(m) ((m) ^ ((((m) >> 4) & 15)))

__device__ __forceinline__ float2 cmul(float2 u, float2 v) {
  return make_float2(fmaf(u.x, v.x, -u.y * v.y), fmaf(u.x, v.y, u.y * v.x));
}

__device__ __forceinline__ float fast_tanh(float x) {
  float e = __expf(2.0f * x);                    // inf-safe
  return 1.0f - 2.0f * __builtin_amdgcn_rcpf(e + 1.0f);
}

__device__ __forceinline__ float2 h2f(__half2 h) { return __half22float2(h); }
__device__ __forceinline__ __half2 f2h(float2 f) { return __float22half2_rn(f); }

// Wave-level ordering fence: LDS ops of a wave execute in order on the DS
// pipe; this only stops compiler reordering (no s_barrier, no cnt drain).
__device__ __forceinline__ void wave_sync() {
  asm volatile("" ::: "memory");
  __builtin_amdgcn_wave_barrier();
  asm volatile("" ::: "memory");
}

// radix-4 DIF butterfly
__device__ __forceinline__ void r4bf(float2 a, float2 b, float2 c, float2 d,
                                     float2& y0, float2& t1, float2& t2, float2& t3) {
  float2 apc = make_float2(a.x + c.x, a.y + c.y);
  float2 amc = make_float2(a.x - c.x, a.y - c.y);
  float2 bpd = make_float2(b.x + d.x, b.y + d.y);
  float2 bmd = make_float2(b.x - d.x, b.y - d.y);
  y0 = make_float2(apc.x + bpd.x, apc.y + bpd.y);
  t1 = make_float2(amc.x + bmd.y, amc.y - bmd.x);  // amc - i*bmd
  t2 = make_float2(apc.x - bpd.x, apc.y - bpd.y);
  t3 = make_float2(amc.x - bmd.y, amc.y + bmd.x);  // amc + i*bmd
}

struct TW {
  float2 a1, a2, a3, b1, b2, b3, c1, c2, c3;
};

__device__ __forceinline__ void load_tw(const float2* __restrict__ W256f, int lane, TW& t) {
  t.a1 = W256f[lane];     t.a2 = W256f[2 * lane];  t.a3 = W256f[3 * lane];
  int p1 = 4 * (lane >> 2);
  t.b1 = W256f[p1];       t.b2 = W256f[2 * p1];    t.b3 = W256f[3 * p1];
  int p2 = 16 * (lane >> 4);
  t.c1 = W256f[p2];       t.c2 = W256f[2 * p2];    t.c3 = W256f[3 * p2];
}

// TWO independent 256-pt forward complex FFTs, stage-interleaved so the
// 8 LDS reads per stage are simultaneously in flight and B's arithmetic
// covers A's load latency. Layout identical to the single-FFT version.
__device__ __forceinline__ void fft256x2(float2& a0, float2& a1, float2& a2, float2& a3,
                                         float2& b0, float2& b1, float2& b2, float2& b3,
                                         float2* __restrict__ bufA,
                                         float2* __restrict__ bufB,
                                         int lane, const TW& tw) {
  float2 y0, t1, t2, t3;
  // stage 0 (s=1, p=lane): register butterfly, scatter 4l..4l+3
  int o0 = 4 * lane;
  r4bf(a0, a1, a2, a3, y0, t1, t2, t3);
  bufA[SWZ(o0)]     = y0;
  bufA[SWZ(o0 + 1)] = cmul(tw.a1, t1);
  bufA[SWZ(o0 + 2)] = cmul(tw.a2, t2);
  bufA[SWZ(o0 + 3)] = cmul(tw.a3, t3);
  r4bf(b0, b1, b2, b3, y0, t1, t2, t3);
  bufB[SWZ(o0)]     = y0;
  bufB[SWZ(o0 + 1)] = cmul(tw.a1, t1);
  bufB[SWZ(o0 + 2)] = cmul(tw.a2, t2);
  bufB[SWZ(o0 + 3)] = cmul(tw.a3, t3);
  wave_sync();
  // stage 1 (s=4)
  {
    float2 ra0 = bufA[SWZ(lane)], ra1 = bufA[SWZ(lane + 64)],
           ra2 = bufA[SWZ(lane + 128)], ra3 = bufA[SWZ(lane + 192)];
    float2 rb0 = bufB[SWZ(lane)], rb1 = bufB[SWZ(lane + 64)],
           rb2 = bufB[SWZ(lane + 128)], rb3 = bufB[SWZ(lane + 192)];
    wave_sync();
    int o = lane + 12 * (lane >> 2);
    r4bf(ra0, ra1, ra2, ra3, y0, t1, t2, t3);
    bufA[SWZ(o)]      = y0;
    bufA[SWZ(o + 4)]  = cmul(tw.b1, t1);
    bufA[SWZ(o + 8)]  = cmul(tw.b2, t2);
    bufA[SWZ(o + 12)] = cmul(tw.b3, t3);
    r4bf(rb0, rb1, rb2, rb3, y0, t1, t2, t3);
    bufB[SWZ(o)]      = y0;
    bufB[SWZ(o + 4)]  = cmul(tw.b1, t1);
    bufB[SWZ(o + 8)]  = cmul(tw.b2, t2);
    bufB[SWZ(o + 12)] = cmul(tw.b3, t3);
  }
  wave_sync();
  // stage 2 (s=16)
  {
    float2 ra0 = bufA[SWZ(lane)], ra1 = bufA[SWZ(lane + 64)],
           ra2 = bufA[SWZ(lane + 128)], ra3 = bufA[SWZ(lane + 192)];
    float2 rb0 = bufB[SWZ(lane)], rb1 = bufB[SWZ(lane + 64)],
           rb2 = bufB[SWZ(lane + 128)], rb3 = bufB[SWZ(lane + 192)];
    wave_sync();
    int o = lane + 48 * (lane >> 4);
    r4bf(ra0, ra1, ra2, ra3, y0, t1, t2, t3);
    bufA[SWZ(o)]      = y0;
    bufA[SWZ(o + 16)] = cmul(tw.c1, t1);
    bufA[SWZ(o + 32)] = cmul(tw.c2, t2);
    bufA[SWZ(o + 48)] = cmul(tw.c3, t3);
    r4bf(rb0, rb1, rb2, rb3, y0, t1, t2, t3);
    bufB[SWZ(o)]      = y0;
    bufB[SWZ(o + 16)] = cmul(tw.c1, t1);
    bufB[SWZ(o + 32)] = cmul(tw.c2, t2);
    bufB[SWZ(o + 48)] = cmul(tw.c3, t3);
  }
  wave_sync();
  // stage 3 (s=64, p=0, twiddle-free): outputs land in register layout
  {
    float2 ra0 = bufA[SWZ(lane)], ra1 = bufA[SWZ(lane + 64)],
           ra2 = bufA[SWZ(lane + 128)], ra3 = bufA[SWZ(lane + 192)];
    float2 rb0 = bufB[SWZ(lane)], rb1 = bufB[SWZ(lane + 64)],
           rb2 = bufB[SWZ(lane + 128)], rb3 = bufB[SWZ(lane + 192)];
    wave_sync();
    r4bf(ra0, ra1, ra2, ra3, a0, a1, a2, a3);
    r4bf(rb0, rb1, rb2, rb3, b0, b1, b2, b3);
  }
}

// W256f[m] = exp(-2pi i m/256), m<256 ; W512s[k] = exp(-2pi i k/512), k<=256
__device__ __forceinline__ void build_tables(float2* W256f, float2* W512s) {
  int tid = threadIdx.x;
  float sv, cv;
  __sincosf(-(TWOPI / 256.0f) * (float)tid, &sv, &cv);
  W256f[tid] = make_float2(cv, sv);
  __sincosf(-(TWOPI / 512.0f) * (float)tid, &sv, &cv);
  W512s[tid] = make_float2(cv, sv);
  if (tid == 0) W512s[256] = make_float2(-1.f, 0.f);
}

// ---------------------------------------------------------------------------
// 1) channel mix: y[b,d,t] = sum_c x[b,c,t] * mixer[c,d]   (fp16 output)
// ---------------------------------------------------------------------------
__global__ __launch_bounds__(256) void mix_kernel(const float* __restrict__ x,
                                                  const float* __restrict__ mixer,
                                                  __half2* __restrict__ y) {
  __shared__ float mm[NCH][NCH];
  for (int i = threadIdx.x; i < NCH * NCH; i += 256)
    ((float*)mm)[i] = mixer[i];
  __syncthreads();
  int b = blockIdx.y;
  int t2 = blockIdx.x * 256 + threadIdx.x;     // float2-pair index
  const float2* xv = (const float2*)x;
  float2 xr[NCH];
#pragma unroll
  for (int c = 0; c < NCH; c++)
    xr[c] = xv[(((size_t)(b * NCH + c)) * T_LEN >> 1) + t2];
#pragma unroll 4
  for (int d = 0; d < NCH; d++) {
    float ax = 0.f, ay = 0.f;
#pragma unroll
    for (int c = 0; c < NCH; c++) {
      ax = fmaf(xr[c].x, mm[c][d], ax);
      ay = fmaf(xr[c].y, mm[c][d], ay);
    }
    y[(((size_t)(b * NCH + d)) * T_LEN >> 1) + t2] = f2h(make_float2(ax, ay));
  }
}

// ---------------------------------------------------------------------------
// 2) forward rfft(512) + register-local scan. Wave = one 4-frame chunk,
//    processed as 2 frame-pairs with interleaved dual FFTs.
// ---------------------------------------------------------------------------
__global__ __launch_bounds__(256, 4) void fft_fwd_kernel(const __half2* __restrict__ y,
                                                         const float* __restrict__ transfer,
                                                         __half2* __restrict__ spec) {
  __shared__ float2 fbuf[FPB][2][NBIN];  // per wave: A and B buffers
  __shared__ float2 W256f[256];
  __shared__ float2 W512s[NBIN];
  build_tables(W256f, W512s);
  __syncthreads();
  int wave = threadIdx.x >> 6, lane = threadIdx.x & 63;
  int cid = blockIdx.x * FPB + wave;     // chunk id 0..16383
  int bc = cid >> 7, blk = cid & (NBLK - 1);
  int ch = bc & (NCH - 1);
  float2* bufA = fbuf[wave][0];
  float2* bufB = fbuf[wave][1];
  TW tw; load_tw(W256f, lane, tw);
  float cwq[4], swq[4], trq[4];
#pragma unroll
  for (int q = 0; q < 4; q++) {
    int k = lane + 64 * q;
    cwq[q] = W512s[k].x; swq[q] = W512s[k].y;
    trq[q] = transfer[ch * NBIN + k];
  }
  float tr256 = transfer[ch * NBIN + 256];
  float2 s[4] = {make_float2(0,0), make_float2(0,0), make_float2(0,0), make_float2(0,0)};
  float s256x = 0.f;
  size_t base2 = ((size_t)bc * T_LEN + (size_t)blk * (FPB * HOP)) >> 1;  // half2 idx
  size_t fb = ((size_t)bc * NFR + (size_t)blk * FPB) * NBIN;
  bool lastchunk = (blk == NBLK - 1);
#pragma unroll
  for (int jj = 0; jj < 2; jj++) {
    int ja = 2 * jj, jb = 2 * jj + 1;
    const __half2* srcA = y + base2 + (size_t)ja * (HOP / 2);
    const __half2* srcB = y + base2 + (size_t)jb * (HOP / 2);
    float2 a0 = h2f(srcA[lane]);
    float2 a1 = h2f(srcA[lane + 64]);
    float2 a2 = h2f(srcA[lane + 128]);
    float2 a3 = h2f(srcA[lane + 192]);
    float2 b0 = h2f(srcB[lane]);
    float2 b1 = h2f(srcB[lane + 64]);
    float2 b2, b3;
    if (lastchunk && jj == 1) {          // zero-padded final half-window
      b2 = make_float2(0, 0); b3 = make_float2(0, 0);
    } else {
      b2 = h2f(srcB[lane + 128]);
      b3 = h2f(srcB[lane + 192]);
    }
    fft256x2(a0, a1, a2, a3, b0, b1, b2, b3, bufA, bufB, lane, tw);
    // mirror staging, both frames
    bufA[lane] = a0; bufA[lane + 64] = a1; bufA[lane + 128] = a2; bufA[lane + 192] = a3;
    bufB[lane] = b0; bufB[lane + 64] = b1; bufB[lane + 128] = b2; bufB[lane + 192] = b3;
    wave_sync();
    float2 amr0 = bufA[(256 - lane) & 255];
    float2 amr1 = bufA[192 - lane];
    float2 amr2 = bufA[128 - lane];
    float2 amr3 = bufA[64 - lane];
    float2 a0b  = bufA[0];
    float2 bmr0 = bufB[(256 - lane) & 255];
    float2 bmr1 = bufB[192 - lane];
    float2 bmr2 = bufB[128 - lane];
    float2 bmr3 = bufB[64 - lane];
    float2 b0b  = bufB[0];
    wave_sync();
    // untangle + scan + store, frame A FIRST (scan order), then frame B
#pragma unroll
    for (int q = 0; q < 4; q++) {
      float2 zk  = (q == 0) ? a0 : (q == 1) ? a1 : (q == 2) ? a2 : a3;
      float2 zmk = (q == 0) ? amr0 : (q == 1) ? amr1 : (q == 2) ? amr2 : amr3;
      float Ex = 0.5f * (zk.x + zmk.x), Ey = 0.5f * (zk.y - zmk.y);
      float dx = 0.5f * (zk.x - zmk.x), dy = 0.5f * (zk.y + zmk.y);
      float Ox = dy, Oy = -dx;
      float Yx = Ex + Ox * cwq[q] - Oy * swq[q];
      float Yy = Ey + Ox * swq[q] + Oy * cwq[q];
      s[q].x = trq[q] * (Yx + s[q].x);
      s[q].y = trq[q] * (Yy + s[q].y);
      spec[fb + (size_t)ja * NBIN + lane + 64 * q] = f2h(s[q]);
    }
    s256x = tr256 * ((a0b.x - a0b.y) + s256x);
    if (lane == 0) spec[fb + (size_t)ja * NBIN + 256] = f2h(make_float2(s256x, 0.f));
#pragma unroll
    for (int q = 0; q < 4; q++) {
      float2 zk  = (q == 0) ? b0 : (q == 1) ? b1 : (q == 2) ? b2 : b3;
      float2 zmk = (q == 0) ? bmr0 : (q == 1) ? bmr1 : (q == 2) ? bmr2 : bmr3;
      float Ex = 0.5f * (zk.x + zmk.x), Ey = 0.5f * (zk.y - zmk.y);
      float dx = 0.5f * (zk.x - zmk.x), dy = 0.5f * (zk.y + zmk.y);
      float Ox = dy, Oy = -dx;
      float Yx = Ex + Ox * cwq[q] - Oy * swq[q];
      float Yy = Ey + Ox * swq[q] + Oy * cwq[q];
      s[q].x = trq[q] * (Yx + s[q].x);
      s[q].y = trq[q] * (Yy + s[q].y);
      spec[fb + (size_t)jb * NBIN + lane + 64 * q] = f2h(s[q]);
    }
    s256x = tr256 * ((b0b.x - b0b.y) + s256x);
    if (lane == 0) spec[fb + (size_t)jb * NBIN + 256] = f2h(make_float2(s256x, 0.f));
    wave_sync();
  }
}

// ---------------------------------------------------------------------------
// 3) carry scan across chunks: C[0]=0; C[i] = final[i-1] + tr^FPB * C[i-1]
// ---------------------------------------------------------------------------
__global__ __launch_bounds__(256) void carry_kernel(const __half2* __restrict__ spec,
                                                    const float* __restrict__ transfer,
                                                    __half2* __restrict__ carries) {
  int tid = blockIdx.x * 256 + threadIdx.x;
  if (tid >= NBC * NBIN) return;
  int bc = tid / NBIN, k = tid - bc * NBIN;
  int ch = bc & (NCH - 1);
  float tr = transfer[ch * NBIN + k];
  float tr2 = tr * tr;
  float tr4 = tr2 * tr2;          // tr^FPB
  const __half2* fin = spec + (size_t)bc * NFR * NBIN + (size_t)(FPB - 1) * NBIN + k;
  __half2* cp = carries + (size_t)bc * NBLK * NBIN + k;
  float cx = 0.f, cy = 0.f;
  for (int i = 0; i < NBLK; i += 16) {
    float2 v[16];
#pragma unroll
    for (int u = 0; u < 16; u++) v[u] = h2f(fin[(size_t)(i + u) * FPB * NBIN]);
#pragma unroll
    for (int u = 0; u < 16; u++) {
      cp[(size_t)(i + u) * NBIN] = f2h(make_float2(cx, cy));
      cx = v[u].x + tr4 * cx;
      cy = v[u].y + tr4 * cy;
    }
  }
}

// ---------------------------------------------------------------------------
// 4) inverse rfft + hann + register OLA. Wave = one 4-frame chunk,
//    processed as 2 frame-pairs with interleaved dual FFTs.
// ---------------------------------------------------------------------------
__global__ __launch_bounds__(256, 4) void fft_inv_kernel(const __half2* __restrict__ spec,
                                                         const __half2* __restrict__ carries,
                                                         const float* __restrict__ transfer,
                                                         const float* __restrict__ gain,
                                                         float* __restrict__ out,
                                                         __half2* __restrict__ bnd) {
  __shared__ float2 fbuf[FPB][2][NBIN];
  __shared__ float2 W256f[256];
  __shared__ float2 W512s[NBIN];
  build_tables(W256f, W512s);
  __syncthreads();
  int wave = threadIdx.x >> 6, lane = threadIdx.x & 63;
  int cid = blockIdx.x * FPB + wave;
  int bc = cid >> 7, blk = cid & (NBLK - 1);
  int ch = bc & (NCH - 1);
  float2* bufA = fbuf[wave][0];
  float2* bufB = fbuf[wave][1];
  TW tw; load_tw(W256f, lane, tw);
  const __half2* crp = carries + ((size_t)bc * NBLK + blk) * NBIN;
  float cwq[4], swq[4], trq[4], trp[4], h0[4], h1[4];
  float2 cv[4];
#pragma unroll
  for (int q = 0; q < 4; q++) {
    int k = lane + 64 * q;
    cwq[q] = W512s[k].x; swq[q] = -W512s[k].y;   // exp(+2pi i k/512)
    trq[q] = transfer[ch * NBIN + k];
    trp[q] = trq[q];
    cv[q] = h2f(crp[k]);
    int t0 = 2 * k, t1 = 2 * k + 1;
    int i0 = (t0 <= 256) ? t0 : 512 - t0;
    int i1 = (t1 <= 256) ? t1 : 512 - t1;
    h0[q] = (0.5f - 0.5f * W512s[i0].x) * (1.0f / 256.0f);
    h1[q] = (0.5f - 0.5f * W512s[i1].x) * (1.0f / 256.0f);
  }
  float tr256 = transfer[ch * NBIN + 256], trp256 = tr256;
  float2 cv256 = h2f(crp[256]);
  float g = gain[ch];
  const __half2* sp0 = spec + ((size_t)bc * NFR + (size_t)blk * FPB) * NBIN;
  float2* outv = (float2*)out;
  size_t obase2 = ((size_t)bc * T_LEN + (size_t)blk * (FPB * HOP)) >> 1;
  __half2* bp = bnd + (((size_t)bc * NBLK + blk) * 2) * (HOP / 2);
  float2 pt0, pt1;                        // previous frame's windowed tail
#pragma unroll
  for (int jj = 0; jj < 2; jj++) {
    int ja = 2 * jj, jb = 2 * jj + 1;
    const __half2* spA = sp0 + (size_t)ja * NBIN;
    const __half2* spB = sp0 + (size_t)jb * NBIN;
    // load + carry fix-up, frame A (powers trp), then frame B (trp*tr)
    float2 YA0 = h2f(spA[lane]);       float2 YB0 = h2f(spB[lane]);
    float2 YA1 = h2f(spA[lane + 64]);  float2 YB1 = h2f(spB[lane + 64]);
    float2 YA2 = h2f(spA[lane + 128]); float2 YB2 = h2f(spB[lane + 128]);
    float2 YA3 = h2f(spA[lane + 192]); float2 YB3 = h2f(spB[lane + 192]);
    float2 yA256 = h2f(spA[256]);      float2 yB256 = h2f(spB[256]);
    YA0.x = fmaf(trp[0], cv[0].x, YA0.x); YA0.y = fmaf(trp[0], cv[0].y, YA0.y);
    YA1.x = fmaf(trp[1], cv[1].x, YA1.x); YA1.y = fmaf(trp[1], cv[1].y, YA1.y);
    YA2.x = fmaf(trp[2], cv[2].x, YA2.x); YA2.y = fmaf(trp[2], cv[2].y, YA2.y);
    YA3.x = fmaf(trp[3], cv[3].x, YA3.x); YA3.y = fmaf(trp[3], cv[3].y, YA3.y);
    yA256.x = fmaf(trp256, cv256.x, yA256.x); yA256.y = fmaf(trp256, cv256.y, yA256.y);
#pragma unroll
    for (int q = 0; q < 4; q++) trp[q] *= trq[q];
    trp256 *= tr256;
    YB0.x = fmaf(trp[0], cv[0].x, YB0.x); YB0.y = fmaf(trp[0], cv[0].y, YB0.y);
    YB1.x = fmaf(trp[1], cv[1].x, YB1.x); YB1.y = fmaf(trp[1], cv[1].y, YB1.y);
    YB2.x = fmaf(trp[2], cv[2].x, YB2.x); YB2.y = fmaf(trp[2], cv[2].y, YB2.y);
    YB3.x = fmaf(trp[3], cv[3].x, YB3.x); YB3.y = fmaf(trp[3], cv[3].y, YB3.y);
    yB256.x = fmaf(trp256, cv256.x, yB256.x); yB256.y = fmaf(trp256, cv256.y, yB256.y);
#pragma unroll
    for (int q = 0; q < 4; q++) trp[q] *= trq[q];
    trp256 *= tr256;
    // mirror staging, both frames
    bufA[lane] = YA0; bufA[lane + 64] = YA1; bufA[lane + 128] = YA2; bufA[lane + 192] = YA3;
    bufB[lane] = YB0; bufB[lane + 64] = YB1; bufB[lane + 128] = YB2; bufB[lane + 192] = YB3;
    if (lane == 0) { bufA[256] = yA256; bufB[256] = yB256; }
    wave_sync();
    float2 amr0 = bufA[256 - lane];
    float2 amr1 = bufA[192 - lane];
    float2 amr2 = bufA[128 - lane];
    float2 amr3 = bufA[64 - lane];
    float2 bmr0 = bufB[256 - lane];
    float2 bmr1 = bufB[192 - lane];
    float2 bmr2 = bufB[128 - lane];
    float2 bmr3 = bufB[64 - lane];
    wave_sync();
    // inverse untangle -> conj'd FFT inputs, both frames
    float2 a0, a1, a2, a3, b0, b1, b2, b3;
#pragma unroll
    for (int q = 0; q < 4; q++) {
      float2 yk  = (q == 0) ? YA0 : (q == 1) ? YA1 : (q == 2) ? YA2 : YA3;
      float2 ymk = (q == 0) ? amr0 : (q == 1) ? amr1 : (q == 2) ? amr2 : amr3;
      float Ex = 0.5f * (yk.x + ymk.x), Ey = 0.5f * (yk.y - ymk.y);
      float dx = 0.5f * (yk.x - ymk.x), dy = 0.5f * (yk.y + ymk.y);
      float Ox = dx * cwq[q] - dy * swq[q];
      float Oy = dx * swq[q] + dy * cwq[q];
      float2 zq = make_float2(Ex - Oy, -(Ey + Ox));
      if (q == 0) a0 = zq; else if (q == 1) a1 = zq; else if (q == 2) a2 = zq; else a3 = zq;
    }
#pragma unroll
    for (int q = 0; q < 4; q++) {
      float2 yk  = (q == 0) ? YB0 : (q == 1) ? YB1 : (q == 2) ? YB2 : YB3;
      float2 ymk = (q == 0) ? bmr0 : (q == 1) ? bmr1 : (q == 2) ? bmr2 : bmr3;
      float Ex = 0.5f * (yk.x + ymk.x), Ey = 0.5f * (yk.y - ymk.y);
      float dx = 0.5f * (yk.x - ymk.x), dy = 0.5f * (yk.y + ymk.y);
      float Ox = dx * cwq[q] - dy * swq[q];
      float Oy = dx * swq[q] + dy * cwq[q];
      float2 zq = make_float2(Ex - Oy, -(Ey + Ox));
      if (q == 0) b0 = zq; else if (q == 1) b1 = zq; else if (q == 2) b2 = zq; else b3 = zq;
    }
    fft256x2(a0, a1, a2, a3, b0, b1, b2, b3, bufA, bufB, lane, tw);
    // windowed time samples + OLA, frame A then frame B
    float2 wA0 = make_float2(a0.x * h0[0], -a0.y * h1[0]);
    float2 wA1 = make_float2(a1.x * h0[1], -a1.y * h1[1]);
    float2 wA2 = make_float2(a2.x * h0[2], -a2.y * h1[2]);
    float2 wA3 = make_float2(a3.x * h0[3], -a3.y * h1[3]);
    if (jj == 0) {
      bp[lane]      = f2h(wA0);           // chunk-leading head -> bnd
      bp[lane + 64] = f2h(wA1);
    } else {
      float2 v0 = make_float2(pt0.x + wA0.x, pt0.y + wA0.y);
      float2 v1 = make_float2(pt1.x + wA1.x, pt1.y + wA1.y);
      outv[obase2 + (size_t)ja * 128 + lane] =
          make_float2(fast_tanh(g * v0.x), fast_tanh(g * v0.y));
      outv[obase2 + (size_t)ja * 128 + lane + 64] =
          make_float2(fast_tanh(g * v1.x), fast_tanh(g * v1.y));
    }
    pt0 = wA2; pt1 = wA3;
    float2 wB0 = make_float2(b0.x * h0[0], -b0.y * h1[0]);
    float2 wB1 = make_float2(b1.x * h0[1], -b1.y * h1[1]);
    float2 wB2 = make_float2(b2.x * h0[2], -b2.y * h1[2]);
    float2 wB3 = make_float2(b3.x * h0[3], -b3.y * h1[3]);
    {
      float2 v0 = make_float2(pt0.x + wB0.x, pt0.y + wB0.y);
      float2 v1 = make_float2(pt1.x + wB1.x, pt1.y + wB1.y);
      outv[obase2 + (size_t)jb * 128 + lane] =
          make_float2(fast_tanh(g * v0.x), fast_tanh(g * v0.y));
      outv[obase2 + (size_t)jb * 128 + lane + 64] =
          make_float2(fast_tanh(g * v1.x), fast_tanh(g * v1.y));
    }
    pt0 = wB2; pt1 = wB3;
    wave_sync();
  }
  bp[128 + lane] = f2h(pt0);              // chunk-trailing tail -> bnd
  bp[192 + lane] = f2h(pt1);
}

// ---------------------------------------------------------------------------
// 5) combine boundary chunks: chunk FPB*b <- bnd[b-1].tail + bnd[b].head
// ---------------------------------------------------------------------------
__global__ __launch_bounds__(256) void final_kernel(const __half* __restrict__ bnd,
                                                    const float* __restrict__ gain,
                                                    float* __restrict__ out) {
  int bc = blockIdx.y, b = blockIdx.x;
  int s = threadIdx.x;
  const __half* base = bnd + ((size_t)bc * NBLK) * 2 * HOP;
  float v = __half2float(base[((size_t)b * 2) * HOP + s]);
  if (b > 0) v += __half2float(base[((size_t)(b - 1) * 2 + 1) * HOP + s]);
  float g = gain[bc & (NCH - 1)];
  out[(size_t)bc * T_LEN + (size_t)b * (FPB * HOP) + s] = fast_tanh(g * v);
}

// ---------------------------------------------------------------------------
extern "C" void kernel_launch(void* const* d_in, const int* in_sizes, int n_in,
                              void* d_out, int out_size, void* d_ws, size_t ws_size,
                              hipStream_t stream) {
  (void)in_sizes; (void)n_in; (void)out_size; (void)ws_size;
  const float* x        = (const float*)d_in[0];
  const float* transfer = (const float*)d_in[1];
  const float* mixer    = (const float*)d_in[2];
  const float* gain     = (const float*)d_in[3];
  float* out = (float*)d_out;

  // ws layout (all fp16):
  //  [spec 67,371,008 B][bnd 16,777,216 B][carries 16,842,752 B][y 33,554,432 B]
  char* p = (char*)d_ws;
  __half2* spec    = (__half2*)p;                       p += (size_t)NBC * NFR * NBIN * 4;
  __half2* bnd     = (__half2*)p;                       p += (size_t)NBC * NBLK * 2 * HOP * 2;
  __half2* carries = (__half2*)p;                       p += (size_t)NBC * NBLK * NBIN * 4;
  __half2* y       = (__half2*)p;

  mix_kernel<<<dim3(T_LEN / 512, NBAT), 256, 0, stream>>>(x, mixer, y);
  fft_fwd_kernel<<<dim3(NBC * NBLK / FPB), 256, 0, stream>>>(y, transfer, spec);
  carry_kernel<<<dim3((NBC * NBIN + 255) / 256), 256, 0, stream>>>(spec, transfer, carries);
  fft_inv_kernel<<<dim3(NBC * NBLK / FPB), 256, 0, stream>>>(spec, carries, transfer, gain, out, (__half2*)bnd);
  final_kernel<<<dim3(NBLK, NBC), 256, 0, stream>>>((const __half*)bnd, gain, out);
}